// Round 5
// baseline (94165.436 us; speedup 1.0000x reference)
//
#include <hip/hip_runtime.h>
#include <stdint.h>

// VanillaRNN — Round 14: cooperative LDS staging, hardened (no inline asm).
//
// Theory (R9/R11/R12 counters): R9's 50ms = 184 cyc/load, serialized — all
// 16 WGs/XCD demand the SAME W line in lockstep, L2 serves the line per-CU
// serially; per-lane strided consume can't hide it. WRITE 15.76GB = L2
// castouts of cycling W (R12 falsified spill: compiler chose 128 VGPR with a
// 256 budget). R11: W is L2-residentable at low WG count. R13 (same theory,
// raw-barrier impl) crashed on a sick node with no counters; this round is
// the SAFE implementation: __syncthreads() only, 2-slot ring, loads issued
// at iteration top so the sync's vmcnt(0) drain finds them complete.
//
// Structure: WG = 512 cols x BPW=4 batch (64 WGs). W streams through a
// 2-slot LDS ring in 32-row/64KB chunks (20 chunks/step, 21 syncs/step).
// Per iter: [issue loads chunk c+2] [consume chunk c from LDS] [ds_write
// chunk c+1] [sync]. Each W line fetched ONCE per WG, coalesced 1KB/wave
// -instr. Consume: W ds_read_b32 bank j%32 (2-way, free) + state float4
// broadcast. 2-slot WAR/RAW safety: both ordered by the single sync/iter.
//
// Numerics BIT-IDENTICAL to R9/R12 (absmax 0.125): per column j ascending
// fmaf chains (xh rows 0..127, +bh, hh rows 0..511), contract(off), Eigen
// tanh, f64 head. Batch accumulators are independent chains.

#define BATCH   256
#define SEQ     1024
#define IN_DIM  128
#define HIDDEN  512
#define CLASSES 128
#define BPW     4                 // batch items per WG
#define NWG     (BATCH / BPW)     // 64
#define CROWS   32                // rows per staged chunk
#define CFLOATS (CROWS * HIDDEN)  // 16384 floats = 64 KB
#define NCH     ((IN_DIM + HIDDEN) / CROWS)  // 20 chunks/step
#define XCH     (IN_DIM / CROWS)  // 4 xh chunks

// ---- Eigen/XLA rational tanh f32, FMA variant — verbatim R5 ----
__device__ __forceinline__ float eigen_tanhf_fma(float ax) {
#pragma clang fp contract(off)
    const float pc = 7.99881172180175781f, mc = -7.99881172180175781f;
    float x = fmaxf(fminf(ax, pc), mc);
    float x2 = x * x;
    float p = __builtin_fmaf(x2, -2.76076847742355e-16f, 2.00018790482477e-13f);
    p = __builtin_fmaf(x2, p, -8.60467152213735e-11f);
    p = __builtin_fmaf(x2, p, 5.12229709037114e-08f);
    p = __builtin_fmaf(x2, p, 1.48572235717979e-05f);
    p = __builtin_fmaf(x2, p, 6.37261928875436e-04f);
    p = __builtin_fmaf(x2, p, 4.89352455891786e-03f);
    p = x * p;
    float q = __builtin_fmaf(x2, 1.19825839466702e-06f, 1.18534705686654e-04f);
    q = __builtin_fmaf(x2, q, 2.26843463243900e-03f);
    q = __builtin_fmaf(x2, q, 4.89352518554385e-03f);
    float r = p / q;
    return (fabsf(ax) < 0.0004f) ? ax : r;
}

struct Regs { float4 r[8]; };   // one thread's 1/512 of a 64KB chunk

__device__ __forceinline__ void load_chunk(Regs& R, const float* __restrict__ src,
                                           int tid) {
#pragma unroll
    for (int i = 0; i < 8; ++i)
        R.r[i] = *(const float4*)(src + (size_t)tid * 4 + (size_t)i * 2048);
}

__device__ __forceinline__ void write_chunk(float* dst, const Regs& R, int tid) {
#pragma unroll
    for (int i = 0; i < 8; ++i)
        *(float4*)(dst + tid * 4 + i * 2048) = R.r[i];
}

// 32 rows: w from LDS (bank j%32, 2 lanes/bank = free), state float4
// broadcast (uniform address). Per-acc chain: ascending rows (frozen == R9).
__device__ __forceinline__ void consume_chunk(const float* __restrict__ wlds,
                                              const float* __restrict__ st,
                                              int j, float (&acc)[4]) {
#pragma clang fp contract(off)
#pragma unroll
    for (int r = 0; r < CROWS; ++r) {
        const float  w  = wlds[r * HIDDEN + j];
        const float4 h4 = *(const float4*)(st + 4 * r);
        acc[0] = __builtin_fmaf(h4.x, w, acc[0]);
        acc[1] = __builtin_fmaf(h4.y, w, acc[1]);
        acc[2] = __builtin_fmaf(h4.z, w, acc[2]);
        acc[3] = __builtin_fmaf(h4.w, w, acc[3]);
    }
}

__global__ __launch_bounds__(512, 2)
void rnn_fast(const float* __restrict__ x,
              const float* __restrict__ W_hh,
              const float* __restrict__ W_xh,
              const float* __restrict__ W_hy,
              const float* __restrict__ b_h,
              const float* __restrict__ b_y,
              float* __restrict__ out)
{
    __shared__ alignas(16) float wl[2][CFLOATS];        // 128 KB ring
    __shared__ alignas(16) float hti[2][HIDDEN][BPW];   // 16 KB [buf][row][batch]
    __shared__ alignas(16) float xti[2][IN_DIM][BPW];   //  4 KB [buf][k][batch]

    const int j = threadIdx.x;   // hidden column
    const int g = blockIdx.x;

    const float bh = b_h[j];
    const int xb = j >> 7, xk = j & (IN_DIM - 1);   // this thread's x element
    const float* px = x + (size_t)(BPW * g + xb) * SEQ * IN_DIM + xk;

    *(float4*)&hti[0][j][0] = make_float4(0.f, 0.f, 0.f, 0.f);
    xti[0][xk][xb] = px[0];

    // prologue: chunk0 -> slot0 (through regs), chunk1 in flight in Rb.
    Regs Ra, Rb;
    load_chunk(Ra, W_xh, j);
    write_chunk(&wl[0][0], Ra, j);          // compiler waits vmcnt for Ra
    load_chunk(Rb, W_xh + CFLOATS, j);
    __syncthreads();                        // slot0 + state init visible
    int pre = 2;   // next global chunk to issue (cyclic 0..NCH-1)

    // Invariant at iter q (global chunk q mod NCH, NCH even):
    //   even q: issue chunk q+2 -> Ra, write chunk q+1 from Rb -> slot q+1&1
    //   odd  q: issue chunk q+2 -> Rb, write chunk q+1 from Ra
    //   consume chunk q from slot q&1.
#define CHUNK_ITER(LD, WR, SLOT, ST, ACC)                                    \
    do {                                                                     \
        const float* csrc = (pre < XCH)                                      \
            ? (W_xh + (size_t)pre * CFLOATS)                                 \
            : (W_hh + (size_t)(pre - XCH) * CFLOATS);                        \
        load_chunk((LD), csrc, j);                                           \
        pre = (pre == NCH - 1) ? 0 : pre + 1;                                \
        consume_chunk(&wl[(SLOT)][0], (ST), j, (ACC));                       \
        write_chunk(&wl[(SLOT) ^ 1][0], (WR), j);                            \
        __syncthreads();                                                     \
    } while (0)

#pragma unroll 1
    for (int t = 0; t < SEQ; ++t) {
        const int cur = t & 1, nxt = cur ^ 1;
        const float* xbase = &xti[cur][0][0];
        const float* hbase = &hti[cur][0][0];

        // ---- xh: chunks 0..3 (rows 0..127 of W_xh) ----
        float a[4] = {0.f, 0.f, 0.f, 0.f};
        CHUNK_ITER(Ra, Rb, 0, xbase + 0 * (CROWS * BPW), a);
        CHUNK_ITER(Rb, Ra, 1, xbase + 1 * (CROWS * BPW), a);
        CHUNK_ITER(Ra, Rb, 0, xbase + 2 * (CROWS * BPW), a);
        CHUNK_ITER(Rb, Ra, 1, xbase + 3 * (CROWS * BPW), a);
        {
#pragma clang fp contract(off)
#pragma unroll
            for (int cc = 0; cc < BPW; ++cc) a[cc] = a[cc] + bh;
        }

        // x_{t+1} prefetch (clamped; LDS store after hh; drained at next sync)
        const int tt = (t + 1 < SEQ) ? t + 1 : t;
        const float xv = px[(size_t)tt * IN_DIM];

        // ---- hh: chunks 4..19 (rows 0..511 of W_hh) ----
        float m[4] = {0.f, 0.f, 0.f, 0.f};
#pragma unroll 1
        for (int p = 0; p < 8; ++p) {
            CHUNK_ITER(Ra, Rb, 0, hbase + (2 * p) * (CROWS * BPW),     m);
            CHUNK_ITER(Rb, Ra, 1, hbase + (2 * p + 1) * (CROWS * BPW), m);
        }

        // ---- h' = tanh(a+m); state handoff, ordered by one extra sync ----
        const float h0 = eigen_tanhf_fma(a[0] + m[0]);
        const float h1 = eigen_tanhf_fma(a[1] + m[1]);
        const float h2 = eigen_tanhf_fma(a[2] + m[2]);
        const float h3 = eigen_tanhf_fma(a[3] + m[3]);
        *(float4*)&hti[nxt][j][0] = make_float4(h0, h1, h2, h3);
        xti[nxt][xk][xb] = xv;
        __syncthreads();
    }

    // ---- head: out[4g+b, c] = h_final[b,:] @ W_hy[:,c] + b_y[c] ----
    // final h in buffer 0 (SEQ even); ascending-i f64 chain, same as R9.
    {
        const int b = j >> 7;            // batch 0..3
        const int c = j & (CLASSES - 1); // class 0..127
        double acc = 0.0;
        for (int i = 0; i < HIDDEN; ++i) {
            acc += (double)hti[0][i][b] * (double)W_hy[(size_t)i * CLASSES + c];
        }
        acc += (double)b_y[c];
        out[(size_t)(BPW * g + b) * CLASSES + c] = (float)acc;
    }
}

extern "C" void kernel_launch(void* const* d_in, const int* in_sizes, int n_in,
                              void* d_out, int out_size, void* d_ws, size_t ws_size,
                              hipStream_t stream)
{
    const float *x, *W_hh, *W_xh, *W_hy, *b_h, *b_y;
    if (in_sizes[0] == BATCH * SEQ * IN_DIM) {
        x    = (const float*)d_in[0];
        W_hh = (const float*)d_in[1];
        W_xh = (const float*)d_in[2];
        W_hy = (const float*)d_in[3];
        b_h  = (const float*)d_in[4];
        b_y  = (const float*)d_in[5];
    } else {
        W_hh = (const float*)d_in[0];
        W_hy = (const float*)d_in[1];
        W_xh = (const float*)d_in[2];
        b_h  = (const float*)d_in[3];
        b_y  = (const float*)d_in[4];
        x    = (const float*)d_in[5];
    }
    float* out = (float*)d_out;
    (void)n_in; (void)out_size; (void)d_ws; (void)ws_size;

    rnn_fast<<<NWG, HIDDEN, 0, stream>>>(x, W_hh, W_xh, W_hy, b_h, b_y, out);
}

// Round 6
// 12641.373 us; speedup vs baseline: 7.4490x; 7.4490x over previous
//
#include <hip/hip_runtime.h>
#include <stdint.h>

// VanillaRNN — Round 15: persistent-W clusters; W leaves HBM/L2 loop entirely.
//
// Evidence chain: R9 50ms = serialized same-address W loads (184 cyc/ld);
// R14 proved it's NOT traffic (FETCH 75 MB, W L2-resident) yet got SLOWER:
// lockstep sync structure + 25% chip utilization + per-sync vmcnt drains.
// Root flaw of R9-R14: every WG re-reads all of W every step. R15 removes W
// from the steady state: each WG holds a 32-column W slice (80 KB) in LDS
// permanently; 16 WGs form a cluster covering all 512 columns for 16 batch
// items; h is exchanged via global (L2/L3) with a per-cluster per-step
// barrier (device-scope atomics, double-buffered hbuf -> race-free).
// Cooperative launch guarantees co-residency (no spin deadlock).
//
// Numerics IDENTICAL to R9/R12 (absmax 0.125): per column j: xh chain
// ascending k=0..127, +b_h, hh chain ascending i=0..511 (one thread owns the
// whole chain), contract(off) fmaf, verbatim Eigen tanh, f64 ascending head.
// h crosses global as exact f32 bits.

#define BATCH   256
#define SEQ     1024
#define IN_DIM  128
#define HIDDEN  512
#define CLASSES 128
#define NWG     256
#define CWGS    16           // WGs per cluster
#define NCL     16           // clusters
#define BPC     16           // batch per cluster
#define COLS    32           // columns per WG
#define NROWS   (IN_DIM + HIDDEN)   // 640

// ---- Eigen/XLA rational tanh f32, FMA variant — verbatim R5 ----
__device__ __forceinline__ float eigen_tanhf_fma(float ax) {
#pragma clang fp contract(off)
    const float pc = 7.99881172180175781f, mc = -7.99881172180175781f;
    float x = fmaxf(fminf(ax, pc), mc);
    float x2 = x * x;
    float p = __builtin_fmaf(x2, -2.76076847742355e-16f, 2.00018790482477e-13f);
    p = __builtin_fmaf(x2, p, -8.60467152213735e-11f);
    p = __builtin_fmaf(x2, p, 5.12229709037114e-08f);
    p = __builtin_fmaf(x2, p, 1.48572235717979e-05f);
    p = __builtin_fmaf(x2, p, 6.37261928875436e-04f);
    p = __builtin_fmaf(x2, p, 4.89352455891786e-03f);
    p = x * p;
    float q = __builtin_fmaf(x2, 1.19825839466702e-06f, 1.18534705686654e-04f);
    q = __builtin_fmaf(x2, q, 2.26843463243900e-03f);
    q = __builtin_fmaf(x2, q, 4.89352518554385e-03f);
    float r = p / q;
    return (fabsf(ax) < 0.0004f) ? ax : r;
}

__global__ __launch_bounds__(512, 2)
void rnn_fast(const float* __restrict__ x,
              const float* __restrict__ W_hh,
              const float* __restrict__ W_xh,
              const float* __restrict__ W_hy,
              const float* __restrict__ b_h,
              const float* __restrict__ b_y,
              float* __restrict__ out,
              unsigned* __restrict__ cnt,     // [NCL][SEQ], zeroed per launch
              float* __restrict__ hbuf)       // [2][BATCH][HIDDEN]
{
    // persistent W slice, blocked [row/4][col][4] -> wave b128 reads are
    // contiguous 512 B (conflict-benign); hb/xb broadcast-read (uniform addr).
    __shared__ alignas(16) float wq[NROWS / 4][COLS][4];   // 80 KB
    __shared__ alignas(16) float hb[BPC][HIDDEN];          // 32 KB
    __shared__ alignas(16) float xb[BPC][IN_DIM];          //  8 KB

    const int tid = threadIdx.x;
    const int g   = blockIdx.x;
    const int c   = tid & 31;          // column within slice
    const int bb  = tid >> 5;          // batch within cluster (0..15)

    // cluster mapping: siblings stride-8 in blockIdx -> same XCD L2 (heuristic
    // only; correctness is agent-scope). Bijective: g = (cl&7) + 8*((cl>>3)*16+cr).
    const int cl = (g & 7) + ((g >> 7) << 3);   // cluster 0..15
    const int cr = (g >> 3) & 15;               // rank in cluster 0..15
    const int bbase = cl << 4;                  // first batch of cluster
    const int col   = (cr << 5) + c;            // this thread's hidden column

    const float bh = b_h[col];
    unsigned* mycnt = cnt + cl * SEQ;
    const float4* wbase = (const float4*)wq + c;   // wq[r4][c][0..3] = wbase[r4*32]

    // ---- one-time: W slice -> LDS (640 rows x 32 cols) ----
    for (int pass = 0; pass < NROWS / 16; ++pass) {
        const int r = pass * 16 + bb;
        const float v = (r < IN_DIM)
            ? W_xh[(size_t)r * HIDDEN + col]
            : W_hh[(size_t)(r - IN_DIM) * HIDDEN + col];
        wq[r >> 2][c][r & 3] = v;
    }
    // h_0 = 0
#pragma unroll
    for (int p = 0; p < 4; ++p)
        *(float4*)&hb[bb][c * 4 + p * 128] = make_float4(0.f, 0.f, 0.f, 0.f);
    __syncthreads();

    for (int t = 0; t < SEQ; ++t) {
        // stage x_t for this cluster's 16 batches (coalesced 512B/half-wave)
        *(float4*)&xb[bb][c * 4] =
            *(const float4*)&x[((size_t)(bbase + bb) * SEQ + t) * IN_DIM + c * 4];

        if (t > 0) {
            // cluster barrier: all 16 siblings finished step t-1.
            if (tid == 0) {
                unsigned* pc = mycnt + (t - 1);
                while (__hip_atomic_load(pc, __ATOMIC_RELAXED,
                                         __HIP_MEMORY_SCOPE_AGENT) < (unsigned)CWGS)
                    __builtin_amdgcn_s_sleep(1);
                (void)__hip_atomic_load(pc, __ATOMIC_ACQUIRE,
                                        __HIP_MEMORY_SCOPE_AGENT);
            }
            __syncthreads();   // publish acquired view to whole WG
            // stage h_{t-1}[16][512] from hbuf parity t&1 (coalesced)
            const float* hsrc = hbuf + ((size_t)(t & 1) * BATCH + bbase) * HIDDEN;
#pragma unroll
            for (int p = 0; p < 4; ++p)
                *(float4*)&hb[bb][c * 4 + p * 128] =
                    *(const float4*)&hsrc[(size_t)bb * HIDDEN + c * 4 + p * 128];
        }
        __syncthreads();

        // ---- frozen chains (thread = batch bb, column col) ----
        float a, m;
        {
#pragma clang fp contract(off)
            a = 0.0f;
            const float4* xrow = (const float4*)&xb[bb][0];
#pragma unroll 8
            for (int r4 = 0; r4 < IN_DIM / 4; ++r4) {
                const float4 w4 = wbase[r4 * 32];
                const float4 x4 = xrow[r4];
                a = __builtin_fmaf(x4.x, w4.x, a);
                a = __builtin_fmaf(x4.y, w4.y, a);
                a = __builtin_fmaf(x4.z, w4.z, a);
                a = __builtin_fmaf(x4.w, w4.w, a);
            }
            a = a + bh;

            m = 0.0f;
            const float4* hrow = (const float4*)&hb[bb][0];
#pragma unroll 8
            for (int r4 = 0; r4 < HIDDEN / 4; ++r4) {
                const float4 w4 = wbase[(IN_DIM / 4 + r4) * 32];
                const float4 h4 = hrow[r4];
                m = __builtin_fmaf(h4.x, w4.x, m);
                m = __builtin_fmaf(h4.y, w4.y, m);
                m = __builtin_fmaf(h4.z, w4.z, m);
                m = __builtin_fmaf(h4.w, w4.w, m);
            }
        }
        const float hnew = eigen_tanhf_fma(a + m);

        // publish h' to the other parity; syncthreads drains the stores
        hbuf[((size_t)((t + 1) & 1) * BATCH + (bbase + bb)) * HIDDEN + col] = hnew;
        __syncthreads();
        if (tid == 0)
            __hip_atomic_fetch_add(mycnt + t, 1u, __ATOMIC_RELEASE,
                                   __HIP_MEMORY_SCOPE_AGENT);
    }

    // ---- head: WG computes batch bbase+cr, all 128 classes (f64, asc i) ----
    if (tid == 0) {
        unsigned* pc = mycnt + (SEQ - 1);
        while (__hip_atomic_load(pc, __ATOMIC_RELAXED,
                                 __HIP_MEMORY_SCOPE_AGENT) < (unsigned)CWGS)
            __builtin_amdgcn_s_sleep(1);
        (void)__hip_atomic_load(pc, __ATOMIC_ACQUIRE, __HIP_MEMORY_SCOPE_AGENT);
    }
    __syncthreads();

    if (tid < CLASSES) {
        const int bfin = bbase + cr;
        const float* hf = hbuf + (size_t)bfin * HIDDEN;   // parity 0 (SEQ even)
        double acc = 0.0;
        for (int i = 0; i < HIDDEN; ++i) {
            acc += (double)hf[i] * (double)W_hy[(size_t)i * CLASSES + tid];
        }
        acc += (double)b_y[tid];
        out[(size_t)bfin * CLASSES + tid] = (float)acc;
    }
}

extern "C" void kernel_launch(void* const* d_in, const int* in_sizes, int n_in,
                              void* d_out, int out_size, void* d_ws, size_t ws_size,
                              hipStream_t stream)
{
    const float *x, *W_hh, *W_xh, *W_hy, *b_h, *b_y;
    if (in_sizes[0] == BATCH * SEQ * IN_DIM) {
        x    = (const float*)d_in[0];
        W_hh = (const float*)d_in[1];
        W_xh = (const float*)d_in[2];
        W_hy = (const float*)d_in[3];
        b_h  = (const float*)d_in[4];
        b_y  = (const float*)d_in[5];
    } else {
        W_hh = (const float*)d_in[0];
        W_hy = (const float*)d_in[1];
        W_xh = (const float*)d_in[2];
        b_h  = (const float*)d_in[3];
        b_y  = (const float*)d_in[4];
        x    = (const float*)d_in[5];
    }
    float* out = (float*)d_out;
    (void)n_in; (void)out_size;

    // d_ws layout: [cnt: NCL*SEQ u32 = 64 KB][hbuf: 2*256*512 f32 = 1 MB]
    unsigned* cnt = (unsigned*)d_ws;
    float* hbuf   = (float*)((char*)d_ws + (size_t)NCL * SEQ * sizeof(unsigned));
    (void)ws_size;

    hipMemsetAsync(d_ws, 0, (size_t)NCL * SEQ * sizeof(unsigned), stream);

    void* args[] = { (void*)&x, (void*)&W_hh, (void*)&W_xh, (void*)&W_hy,
                     (void*)&b_h, (void*)&b_y, (void*)&out,
                     (void*)&cnt, (void*)&hbuf };
    hipLaunchCooperativeKernel((const void*)rnn_fast, dim3(NWG), dim3(512),
                               args, 0, stream);
}